// Round 8
// baseline (198.632 us; speedup 1.0000x reference)
//
#include <hip/hip_runtime.h>
#include <math.h>

// ---------------------------------------------------------------------------
// Problem constants
// ---------------------------------------------------------------------------
#define NROWS 65536          // B*NAG = 8192*8
#define NB    8192           // B
// workspace layout (float offsets)
#define STAT_OFF  0          // 448 floats: asum asq usum usq vsum vsq cross
#define P2T_OFF   448        // 384 floats: po2^T [6][64]  (stat-independent)
#define WPACK_OFF 832        // 5952 frags x 8 ushort = 47616 ushorts
// d_out layout (float offsets): x_out, h, KL
#define OUT_XOUT 0
#define OUT_H    917504
#define OUT_KL   5111808

typedef __attribute__((ext_vector_type(8))) short bhalf8;
typedef __attribute__((ext_vector_type(4))) float floatx4;
typedef __attribute__((ext_vector_type(4))) unsigned short u16x4;

__device__ __forceinline__ float sigmf(float x) { return 1.0f / (1.0f + __expf(-x)); }
__device__ __forceinline__ float tanhfast(float x) {
    x = fminf(fmaxf(x, -15.f), 15.f);
    float e = __expf(-2.f * x);
    return (1.f - e) / (1.f + e);
}
__device__ __forceinline__ unsigned short f2bf(float f) {   // RNE fp32->bf16
    unsigned int u = __float_as_uint(f);
    u += 0x7FFFu + ((u >> 16) & 1u);
    return (unsigned short)(u >> 16);
}
__device__ __forceinline__ float bf2f(unsigned short s) {
    return __uint_as_float(((unsigned int)s) << 16);
}
__device__ __forceinline__ bhalf8 pack8(float4 a, float4 b) {
    bhalf8 r;
    r[0] = (short)f2bf(a.x); r[1] = (short)f2bf(a.y);
    r[2] = (short)f2bf(a.z); r[3] = (short)f2bf(a.w);
    r[4] = (short)f2bf(b.x); r[5] = (short)f2bf(b.y);
    r[6] = (short)f2bf(b.z); r[7] = (short)f2bf(b.w);
    return r;
}

// ---------------------------------------------------------------------------
// K0 (k_prep): zero stats + po2^T into ws + pack ALL weights into bf16 MFMA
// B-fragment order.  Fragment = 16 cols x 32 k; lane (n=lane&15, quad=lane>>4)
// holds 8 contiguous bf16 for k = quad*8+j.   24 blocks -> single pass.
// ---------------------------------------------------------------------------
__global__ void k_prep(const float* __restrict__ fc1_w,
                       const float* __restrict__ w_ih, const float* __restrict__ w_hh,
                       const float* __restrict__ aw1_w, const float* __restrict__ po1_w,
                       const float* __restrict__ aw2_w, const float* __restrict__ fc2_w,
                       const float* __restrict__ po2_w,
                       float* __restrict__ ws)
{
    const int t = threadIdx.x;
    if (blockIdx.x == 0) {
        for (int i = t; i < 448; i += 256) ws[STAT_OFF + i] = 0.f;
        for (int i = t; i < 384; i += 256) {
            int d = i >> 6, c = i & 63;
            ws[P2T_OFF + i] = po2_w[c * 6 + d];     // po2^T [6][64]
        }
    }

    unsigned short* wpk = (unsigned short*)(ws + WPACK_OFF);
    for (int f = blockIdx.x * 256 + t; f < 5952; f += gridDim.x * 256) {
        int lane, c, tile;
        const float* src;
        int colbase, krowstride, kofs = 0, kmax = 1 << 30, colmax = 16;
        if (f < 768) {            // wp1
            tile = f / 192; c = (f % 192) / 64; lane = f % 64;
            src = fc1_w; krowstride = 64; colbase = tile * 16;
        } else if (f < 3840) {    // wp2
            int f2 = f - 768;
            tile = f2 / 128; c = (f2 % 128) / 64; lane = f2 % 64;
            if (tile < 12) { src = w_ih; colbase = tile * 16; }
            else           { src = w_hh; colbase = (tile - 12) * 16; }
            krowstride = 192;
        } else if (f < 5376) {    // wp3
            int f3 = f - 3840;
            tile = f3 / 128; c = (f3 % 128) / 64; lane = f3 % 64;
            if (tile < 4)       { src = aw1_w; colbase = tile * 16; }
            else if (tile < 8)  { src = po1_w; colbase = (tile - 4) * 16; }
            else                { src = po1_w; colbase = (tile - 8) * 16; kofs = 64; }
            krowstride = 64;
        } else if (f < 5760) {    // wpa2
            int f4 = f - 5376;
            tile = f4 / 128; c = (f4 % 128) / 64; lane = f4 % 64;
            src = aw2_w; krowstride = 48; colbase = tile * 16;
        } else {                  // wpf2
            int f5 = f - 5760;
            c = f5 / 64; lane = f5 % 64;
            src = fc2_w; krowstride = 14; colbase = 0;
            kmax = 88; colmax = 14;
        }
        int n = lane & 15, quad = lane >> 4;
        int col = colbase + n;
        unsigned short o[8];
        #pragma unroll
        for (int j = 0; j < 8; j++) {
            int k = c * 32 + quad * 8 + j + kofs;
            float v = (k < kmax && n < colmax) ? src[(size_t)k * krowstride + col] : 0.f;
            o[j] = f2bf(v);
        }
        u16x4 lo, hi;
        lo.x = o[0]; lo.y = o[1]; lo.z = o[2]; lo.w = o[3];
        hi.x = o[4]; hi.y = o[5]; hi.z = o[6]; hi.w = o[7];
        *(u16x4*)&wpk[f * 8]     = lo;
        *(u16x4*)&wpk[f * 8 + 4] = hi;
    }
}

// ---------------------------------------------------------------------------
// K1: fc1 -> GRU -> h + BN stat partials.  64 rows/block, 256 thr (4 waves,
// 1 m-tile/wave), grid 1024 -> 4 blocks/CU (grid was the occupancy limiter).
// A-frags of inp/h_in direct from global; x/h round-trip via wave-private
// LDS rows (stride 80).  LDS ~12 KB, VGPR ~60, 2 barriers.
// ---------------------------------------------------------------------------
__global__ __launch_bounds__(256, 4) void k_front(
    const float* __restrict__ inp, const float* __restrict__ hin,
    const float* __restrict__ fc1_b,
    const float* __restrict__ b_ih, const float* __restrict__ b_hh,
    const float* __restrict__ aw1_b,
    float* __restrict__ h_out, float* __restrict__ ws)
{
    __shared__ __align__(16) unsigned short s_xb[64 * 80];  // x, then h (wave-private rows)
    __shared__ float s_stat[448];

    const int t = threadIdx.x;
    const int row0 = blockIdx.x * 64;
    const int lane = t & 63;
    const int w = t >> 6;
    const int n16 = lane & 15;
    const int quad = lane >> 4;
    const int mrow = w * 16 + n16;

    for (int i = t; i < 448; i += 256) s_stat[i] = 0.f;
    __syncthreads();

    const bhalf8* wp1 = (const bhalf8*)((const unsigned short*)(ws + WPACK_OFF));
    const bhalf8* wp2 = wp1 + 768;
    const bhalf8* wp3 = wp1 + 3840;

    // ---- A-frag direct global loads ----
    bhalf8 ai[3], ahf[2];
    {
        const float* gi = inp + (size_t)(row0 + mrow) * 96 + quad * 8;
        #pragma unroll
        for (int kc = 0; kc < 3; kc++)
            ai[kc] = pack8(*(const float4*)&gi[kc * 32], *(const float4*)&gi[kc * 32 + 4]);
        const float* gh = hin + (size_t)(row0 + mrow) * 64 + quad * 8;
        #pragma unroll
        for (int kc = 0; kc < 2; kc++)
            ahf[kc] = pack8(*(const float4*)&gh[kc * 32], *(const float4*)&gh[kc * 32 + 4]);
    }

    // ---- P1: x = relu(inp @ fc1_w + b) ----
    #pragma unroll
    for (int g = 0; g < 4; g++) {
        int col = g * 16 + n16;
        floatx4 d = {0.f, 0.f, 0.f, 0.f};
        d = __builtin_amdgcn_mfma_f32_16x16x32_bf16(ai[0], wp1[(g * 3 + 0) * 64 + lane], d, 0, 0, 0);
        d = __builtin_amdgcn_mfma_f32_16x16x32_bf16(ai[1], wp1[(g * 3 + 1) * 64 + lane], d, 0, 0, 0);
        d = __builtin_amdgcn_mfma_f32_16x16x32_bf16(ai[2], wp1[(g * 3 + 2) * 64 + lane], d, 0, 0, 0);
        float bb = fc1_b[col];
        #pragma unroll
        for (int q = 0; q < 4; q++)
            s_xb[(w * 16 + quad * 4 + q) * 80 + col] = f2bf(fmaxf(d[q] + bb, 0.f));
    }
    // x A-frags (own-wave rows; same-wave DS ordering)
    bhalf8 ax[2];
    ax[0] = *(const bhalf8*)&s_xb[mrow * 80 + 0  + quad * 8];
    ax[1] = *(const bhalf8*)&s_xb[mrow * 80 + 32 + quad * 8];

    // ---- P2 per-g: gates -> h (h overlays x; x lives in ax regs) ----
    #pragma unroll
    for (int g = 0; g < 4; g++) {
        int col = g * 16 + n16;
        floatx4 dr = {0.f, 0.f, 0.f, 0.f}, dz = {0.f, 0.f, 0.f, 0.f};
        floatx4 dn = {0.f, 0.f, 0.f, 0.f}, dh = {0.f, 0.f, 0.f, 0.f};
        dr = __builtin_amdgcn_mfma_f32_16x16x32_bf16(ax[0],  wp2[((0 + g) * 2 + 0) * 64 + lane], dr, 0, 0, 0);
        dr = __builtin_amdgcn_mfma_f32_16x16x32_bf16(ax[1],  wp2[((0 + g) * 2 + 1) * 64 + lane], dr, 0, 0, 0);
        dr = __builtin_amdgcn_mfma_f32_16x16x32_bf16(ahf[0], wp2[((12 + g) * 2 + 0) * 64 + lane], dr, 0, 0, 0);
        dr = __builtin_amdgcn_mfma_f32_16x16x32_bf16(ahf[1], wp2[((12 + g) * 2 + 1) * 64 + lane], dr, 0, 0, 0);
        dz = __builtin_amdgcn_mfma_f32_16x16x32_bf16(ax[0],  wp2[((4 + g) * 2 + 0) * 64 + lane], dz, 0, 0, 0);
        dz = __builtin_amdgcn_mfma_f32_16x16x32_bf16(ax[1],  wp2[((4 + g) * 2 + 1) * 64 + lane], dz, 0, 0, 0);
        dz = __builtin_amdgcn_mfma_f32_16x16x32_bf16(ahf[0], wp2[((16 + g) * 2 + 0) * 64 + lane], dz, 0, 0, 0);
        dz = __builtin_amdgcn_mfma_f32_16x16x32_bf16(ahf[1], wp2[((16 + g) * 2 + 1) * 64 + lane], dz, 0, 0, 0);
        dn = __builtin_amdgcn_mfma_f32_16x16x32_bf16(ax[0],  wp2[((8 + g) * 2 + 0) * 64 + lane], dn, 0, 0, 0);
        dn = __builtin_amdgcn_mfma_f32_16x16x32_bf16(ax[1],  wp2[((8 + g) * 2 + 1) * 64 + lane], dn, 0, 0, 0);
        dh = __builtin_amdgcn_mfma_f32_16x16x32_bf16(ahf[0], wp2[((20 + g) * 2 + 0) * 64 + lane], dh, 0, 0, 0);
        dh = __builtin_amdgcn_mfma_f32_16x16x32_bf16(ahf[1], wp2[((20 + g) * 2 + 1) * 64 + lane], dh, 0, 0, 0);
        float br_ = b_ih[col] + b_hh[col];
        float bz_ = b_ih[64 + col] + b_hh[64 + col];
        float bin_ = b_ih[128 + col];
        float bhn_ = b_hh[128 + col];
        #pragma unroll
        for (int q = 0; q < 4; q++) {
            int lrow = w * 16 + quad * 4 + q;
            size_t grow = (size_t)(row0 + lrow);
            float r  = sigmf(dr[q] + br_);
            float z  = sigmf(dz[q] + bz_);
            float nt = tanhfast(dn[q] + bin_ + r * (dh[q] + bhn_));
            float hp = hin[grow * 64 + col];
            float h  = (1.f - z) * nt + z * hp;
            h_out[grow * 64 + col] = h;
            s_xb[lrow * 80 + col] = f2bf(h);
        }
    }

    // h A-frags (own-wave rows)
    bhalf8 hh0 = *(const bhalf8*)&s_xb[mrow * 80 + 0  + quad * 8];
    bhalf8 hh1 = *(const bhalf8*)&s_xb[mrow * 80 + 32 + quad * 8];

    // ---- P3 per-g: a1/U/V stats only ----
    #pragma unroll
    for (int g = 0; g < 4; g++) {
        int col = g * 16 + n16;
        floatx4 da = {0.f, 0.f, 0.f, 0.f}, du = {0.f, 0.f, 0.f, 0.f}, dv = {0.f, 0.f, 0.f, 0.f};
        da = __builtin_amdgcn_mfma_f32_16x16x32_bf16(hh0, wp3[(g * 2 + 0) * 64 + lane], da, 0, 0, 0);
        da = __builtin_amdgcn_mfma_f32_16x16x32_bf16(hh1, wp3[(g * 2 + 1) * 64 + lane], da, 0, 0, 0);
        du = __builtin_amdgcn_mfma_f32_16x16x32_bf16(hh0, wp3[((4 + g) * 2 + 0) * 64 + lane], du, 0, 0, 0);
        du = __builtin_amdgcn_mfma_f32_16x16x32_bf16(hh1, wp3[((4 + g) * 2 + 1) * 64 + lane], du, 0, 0, 0);
        dv = __builtin_amdgcn_mfma_f32_16x16x32_bf16(hh0, wp3[((8 + g) * 2 + 0) * 64 + lane], dv, 0, 0, 0);
        dv = __builtin_amdgcn_mfma_f32_16x16x32_bf16(hh1, wp3[((8 + g) * 2 + 1) * 64 + lane], dv, 0, 0, 0);
        float ab = aw1_b[col];
        float s1 = 0.f, s2 = 0.f, su = 0.f, suq = 0.f, sv = 0.f, svq = 0.f;
        #pragma unroll
        for (int q = 0; q < 4; q++) {
            float a = da[q] + ab; s1 += a; s2 += a * a;
            float uv = du[q]; su += uv; suq += uv * uv;
            float vv = dv[q]; sv += vv; svq += vv * vv;
        }
        // cross term per 8-row b-group: quads (0,1)=rows 0-7, (2,3)=rows 8-15
        float u8 = su + __shfl_xor(su, 16, 64);
        float v8 = sv + __shfl_xor(sv, 16, 64);
        if ((quad & 1) == 0)
            atomicAdd(&s_stat[384 + col], u8 * v8 * (1.f / 64.f));
        float t1 = s1 + __shfl_xor(s1, 16, 64);   t1 += __shfl_xor(t1, 32, 64);
        float t2 = s2 + __shfl_xor(s2, 16, 64);   t2 += __shfl_xor(t2, 32, 64);
        float t3 = u8 + __shfl_xor(u8, 32, 64);
        float t4 = suq + __shfl_xor(suq, 16, 64); t4 += __shfl_xor(t4, 32, 64);
        float t5 = v8 + __shfl_xor(v8, 32, 64);
        float t6 = svq + __shfl_xor(svq, 16, 64); t6 += __shfl_xor(t6, 32, 64);
        if (quad == 0) {
            atomicAdd(&s_stat[col], t1);
            atomicAdd(&s_stat[64 + col], t2);
            atomicAdd(&s_stat[128 + col], t3);
            atomicAdd(&s_stat[192 + col], t4);
            atomicAdd(&s_stat[256 + col], t5);
            atomicAdd(&s_stat[320 + col], t6);
        }
    }
    __syncthreads();
    if (t < 64) {
        float* gs = ws + STAT_OFF;
        #pragma unroll
        for (int q = 0; q < 7; q++)
            atomicAdd(&gs[q * 64 + t], s_stat[q * 64 + t]);
    }
}

// ---------------------------------------------------------------------------
// K2 (k_heads): fused stats-finalize + actor + critic head.  32 rows (4 b)
// per block, 256 thr (4 waves; MFMA phases on waves 0-1, critic/KL on all 4).
// po2^T read from GLOBAL ws (wave-uniform -> s_load, no LDS traffic).
// LDS ~29.6 KB -> 5 blocks/CU x 4 waves = 20 waves/CU.
// ---------------------------------------------------------------------------
__global__ __launch_bounds__(256) void k_heads(
    const float* __restrict__ h_glob, const float* __restrict__ noise,
    const float* __restrict__ aw1_b, const float* __restrict__ aw2_b,
    const float* __restrict__ fc2_b, const float* __restrict__ po2_b,
    const float* __restrict__ aw_g, const float* __restrict__ aw_be,
    const float* __restrict__ po_g, const float* __restrict__ po_be,
    const float* __restrict__ po1_b,
    const float* __restrict__ ws, float* __restrict__ out)
{
    __shared__ __align__(16) unsigned short s_hb[32 * 104]; // h | c | zero-pad
    __shared__ __align__(16) unsigned short s_Ub[32 * 80];  // bf16 psc*U
    __shared__ __align__(16) unsigned short s_Vb[32 * 80];  // bf16 psc*V + psh
    __shared__ float s_ms[32 * 48];                         // mu | sigma
    __shared__ __align__(16) float s_buf[32 * 48];          // s_ab (str 80) then s_out
    __shared__ float s_dv[256];                             // asc ash psc psh
    __shared__ float s_kl[32];

    const int t = threadIdx.x;
    const int row0 = blockIdx.x * 32;
    const int b0 = blockIdx.x * 4;
    const int lane = t & 63;
    const int w = t >> 6;
    const int n16 = lane & 15;
    const int quad = lane >> 4;
    const int mrow = w * 16 + n16;      // valid for w < 2

    // ---- derive BN scale/shift from global stats ----
    if (t < 64) {
        const float* st = ws + STAT_OFF;
        const float invN = 1.f / 65536.f;
        float am = st[t] * invN;
        float av = st[64 + t] * invN - am * am;
        float asc = aw_g[t] * rsqrtf(av + 1e-5f);
        s_dv[t] = asc;
        s_dv[64 + t] = aw_be[t] - asc * am;
        float Eu = st[128 + t] * invN;
        float vu = st[192 + t] * invN - Eu * Eu;
        float Ev = st[256 + t] * invN;
        float vv = st[320 + t] * invN - Ev * Ev;
        float cov = st[384 + t] * (1.f / 8192.f) - Eu * Ev;
        float my = Eu + Ev + po1_b[t];
        float vy = vu + vv + 2.f * cov;
        float psc = po_g[t] * rsqrtf(vy + 1e-5f);
        s_dv[128 + t] = psc;
        s_dv[192 + t] = po_be[t] + psc * (po1_b[t] - my);
    }

    // ---- stage h -> bf16 (cols 0-63); zero pad cols 88-95 ----
    {
        const float* gh = h_glob + (size_t)row0 * 64;
        for (int i = t; i < 512; i += 256) {
            int r = i >> 4, c4 = (i & 15) * 4;
            float4 v = *(const float4*)&gh[r * 64 + c4];
            u16x4 p; p.x = f2bf(v.x); p.y = f2bf(v.y); p.z = f2bf(v.z); p.w = f2bf(v.w);
            *(u16x4*)&s_hb[r * 104 + c4] = p;
        }
        if (t < 64) {
            int r = t >> 1, c4 = 88 + (t & 1) * 4;
            u16x4 z; z.x = 0; z.y = 0; z.z = 0; z.w = 0;
            *(u16x4*)&s_hb[r * 104 + c4] = z;
        }
    }
    __syncthreads();

    const bhalf8* wp3  = ((const bhalf8*)((const unsigned short*)(ws + WPACK_OFF))) + 3840;
    const bhalf8* wpa2 = wp3 + 1536;
    const bhalf8* wpf2 = wpa2 + 384;
    unsigned short* s_ab = (unsigned short*)s_buf;    // stride 80, dead before C

    // ---- phase A (waves 0-1): a1/U'/V' via MFMA ----
    if (w < 2) {
        bhalf8 ah0 = *(const bhalf8*)&s_hb[mrow * 104 + 0  + quad * 8];
        bhalf8 ah1 = *(const bhalf8*)&s_hb[mrow * 104 + 32 + quad * 8];
        #pragma unroll
        for (int g = 0; g < 4; g++) {
            int col = g * 16 + n16;
            floatx4 da = {0.f, 0.f, 0.f, 0.f}, duu = {0.f, 0.f, 0.f, 0.f}, dvv = {0.f, 0.f, 0.f, 0.f};
            da  = __builtin_amdgcn_mfma_f32_16x16x32_bf16(ah0, wp3[(g * 2 + 0) * 64 + lane], da, 0, 0, 0);
            da  = __builtin_amdgcn_mfma_f32_16x16x32_bf16(ah1, wp3[(g * 2 + 1) * 64 + lane], da, 0, 0, 0);
            duu = __builtin_amdgcn_mfma_f32_16x16x32_bf16(ah0, wp3[((4 + g) * 2 + 0) * 64 + lane], duu, 0, 0, 0);
            duu = __builtin_amdgcn_mfma_f32_16x16x32_bf16(ah1, wp3[((4 + g) * 2 + 1) * 64 + lane], duu, 0, 0, 0);
            dvv = __builtin_amdgcn_mfma_f32_16x16x32_bf16(ah0, wp3[((8 + g) * 2 + 0) * 64 + lane], dvv, 0, 0, 0);
            dvv = __builtin_amdgcn_mfma_f32_16x16x32_bf16(ah1, wp3[((8 + g) * 2 + 1) * 64 + lane], dvv, 0, 0, 0);
            float ab = aw1_b[col];
            float asc = s_dv[col], ash = s_dv[64 + col];
            float psc = s_dv[128 + col], psh = s_dv[192 + col];
            #pragma unroll
            for (int q = 0; q < 4; q++) {
                int lrow = w * 16 + quad * 4 + q;
                s_ab[lrow * 80 + col] = f2bf(fmaxf(asc * (da[q] + ab) + ash, 0.f));
                s_Ub[lrow * 80 + col] = f2bf(psc * duu[q]);
                s_Vb[lrow * 80 + col] = f2bf(psc * dvv[q] + psh);
            }
        }
        // ---- phase B1 (waves 0-1): aw = a @ aw2_w + b -> mu / sigma ----
        bhalf8 aa0 = *(const bhalf8*)&s_ab[mrow * 80 + 0  + quad * 8];
        bhalf8 aa1 = *(const bhalf8*)&s_ab[mrow * 80 + 32 + quad * 8];
        #pragma unroll
        for (int g = 0; g < 3; g++) {
            floatx4 d = {0.f, 0.f, 0.f, 0.f};
            d = __builtin_amdgcn_mfma_f32_16x16x32_bf16(aa0, wpa2[(g * 2 + 0) * 64 + lane], d, 0, 0, 0);
            d = __builtin_amdgcn_mfma_f32_16x16x32_bf16(aa1, wpa2[(g * 2 + 1) * 64 + lane], d, 0, 0, 0);
            int col = g * 16 + n16;
            float bb = aw2_b[col];
            #pragma unroll
            for (int q = 0; q < 4; q++) {
                int lrow = w * 16 + quad * 4 + q;
                float v = d[q] + bb;
                s_ms[lrow * 48 + col] = (col < 24) ? v : fmaxf(__expf(v), 0.2f);
            }
        }
    }
    __syncthreads();

    // ---- phase B2 (all waves): c = mu + sqrt(sigma)*noise -> s_hb cols 64-87 ----
    for (int i = t; i < 768; i += 256) {
        int r = i / 24, m = i - r * 24;
        float c = s_ms[r * 48 + m] + sqrtf(s_ms[r * 48 + 24 + m]) * noise[(size_t)(row0 + r) * 24 + m];
        s_hb[r * 104 + 64 + m] = f2bf(c);
    }
    __syncthreads();

    // ---- phase B3 (waves 0-1): x_out = [h,c] @ fc2_w + b ----
    if (w < 2) {
        bhalf8 hc0 = *(const bhalf8*)&s_hb[mrow * 104 + 0  + quad * 8];
        bhalf8 hc1 = *(const bhalf8*)&s_hb[mrow * 104 + 32 + quad * 8];
        bhalf8 hc2 = *(const bhalf8*)&s_hb[mrow * 104 + 64 + quad * 8];
        floatx4 d = {0.f, 0.f, 0.f, 0.f};
        d = __builtin_amdgcn_mfma_f32_16x16x32_bf16(hc0, wpf2[0 * 64 + lane], d, 0, 0, 0);
        d = __builtin_amdgcn_mfma_f32_16x16x32_bf16(hc1, wpf2[1 * 64 + lane], d, 0, 0, 0);
        d = __builtin_amdgcn_mfma_f32_16x16x32_bf16(hc2, wpf2[2 * 64 + lane], d, 0, 0, 0);
        if (n16 < 14) {
            float bb = fc2_b[n16];
            float* xout = out + OUT_XOUT;
            #pragma unroll
            for (int q = 0; q < 4; q++) {
                size_t grow = (size_t)(row0 + w * 16 + quad * 4 + q);
                xout[grow * 14 + n16] = d[q] + bb;
            }
        }
    }
    __syncthreads();   // s_ab dead -> s_out overlay safe; s_Ub/s_Vb visible

    // ---- phase C (all 4 waves): critic pairwise + po2.  1 (b,i,j)/thread ----
    float* s_out = s_buf;              // stride 48
    {
        const float* p2t = ws + P2T_OFF;   // GLOBAL uniform -> s_load
        const int bl = t >> 6;             // local b (0..3)
        const int rem = t & 63;
        const int i_ = rem >> 3;           // i (0..7)
        const int j_ = rem & 7;            // j (0..7)
        float acc[6] = {0.f, 0.f, 0.f, 0.f, 0.f, 0.f};
        #pragma unroll
        for (int c = 0; c < 64; c += 8) {
            bhalf8 vb = *(const bhalf8*)&s_Vb[(bl * 8 + i_) * 80 + c];
            bhalf8 ub = *(const bhalf8*)&s_Ub[(bl * 8 + j_) * 80 + c];
            float p[8];
            #pragma unroll
            for (int q = 0; q < 8; q++)
                p[q] = fmaxf(bf2f((unsigned short)ub[q]) + bf2f((unsigned short)vb[q]), 0.f);
            #pragma unroll
            for (int d = 0; d < 6; d++) {
                const float* wd = &p2t[d * 64 + c];
                float s = 0.f;
                #pragma unroll
                for (int q = 0; q < 8; q++) s += p[q] * wd[q];
                acc[d] += s;
            }
        }
        #pragma unroll
        for (int d = 0; d < 6; d++)
            s_out[(bl * 8 + i_) * 48 + j_ * 6 + d] = acc[d] + po2_b[d];
    }
    __syncthreads();

    // ---- KL ----
    if (t < 32) {
        float s = 0.f;
        #pragma unroll 4
        for (int m = 0; m < 24; m++) {
            float mu0 = s_ms[t * 48 + m];
            float sg0 = s_ms[t * 48 + 24 + m];
            float mu1 = s_out[t * 48 + m];
            float sg1 = fmaxf(__expf(s_out[t * 48 + 24 + m]), 0.2f);
            float d0 = mu0 - mu1;
            s += __logf(sg1 / sg0) + (sg0 + d0 * d0) / sg1 - 1.f;
        }
        s_kl[t] = s;
    }
    __syncthreads();
    if (t < 4) {
        float s = 0.f;
        #pragma unroll
        for (int i = 0; i < 8; i++) s += s_kl[t * 8 + i];
        out[OUT_KL + b0 + t] = s * (0.5f / 192.f);
    }
}

// ---------------------------------------------------------------------------
extern "C" void kernel_launch(void* const* d_in, const int* in_sizes, int n_in,
                              void* d_out, int out_size, void* d_ws, size_t ws_size,
                              hipStream_t stream)
{
    (void)in_sizes; (void)n_in; (void)out_size; (void)ws_size;
    const float* inp   = (const float*)d_in[0];
    const float* hin   = (const float*)d_in[1];
    const float* noise = (const float*)d_in[2];
    const float* fc1_w = (const float*)d_in[3];
    const float* fc1_b = (const float*)d_in[4];
    const float* w_ih  = (const float*)d_in[5];
    const float* w_hh  = (const float*)d_in[6];
    const float* b_ih  = (const float*)d_in[7];
    const float* b_hh  = (const float*)d_in[8];
    const float* aw1_w = (const float*)d_in[9];
    const float* aw1_b = (const float*)d_in[10];
    const float* aw_g  = (const float*)d_in[11];
    const float* aw_be = (const float*)d_in[12];
    const float* aw2_w = (const float*)d_in[13];
    const float* aw2_b = (const float*)d_in[14];
    const float* po1_w = (const float*)d_in[15];
    const float* po1_b = (const float*)d_in[16];
    const float* po_g  = (const float*)d_in[17];
    const float* po_be = (const float*)d_in[18];
    const float* po2_w = (const float*)d_in[19];
    const float* po2_b = (const float*)d_in[20];
    const float* fc2_w = (const float*)d_in[21];
    const float* fc2_b = (const float*)d_in[22];
    float* out = (float*)d_out;
    float* ws  = (float*)d_ws;

    hipLaunchKernelGGL(k_prep,  dim3(24),   dim3(256), 0, stream,
                       fc1_w, w_ih, w_hh, aw1_w, po1_w, aw2_w, fc2_w, po2_w, ws);
    hipLaunchKernelGGL(k_front, dim3(1024), dim3(256), 0, stream,
                       inp, hin, fc1_b, b_ih, b_hh, aw1_b, out + OUT_H, ws);
    hipLaunchKernelGGL(k_heads, dim3(2048), dim3(256), 0, stream,
                       out + OUT_H, noise, aw1_b, aw2_b, fc2_b, po2_b,
                       aw_g, aw_be, po_g, po_be, po1_b, ws, out);
}